// Round 9
// baseline (214.144 us; speedup 1.0000x reference)
//
#include <hip/hip_runtime.h>
#include <math.h>
#include <float.h>

#define K_CODES 8192
#define C_DIM   256
#define N_TOK   16384
#define B_      16
#define H_      32
#define W_      32
#define HW      1024
#define KSPLIT  16

typedef short  short8   __attribute__((ext_vector_type(8)));
typedef float  floatx16 __attribute__((ext_vector_type(16)));

__device__ inline ushort f32_to_bf16_rne(float x) {
    union { float f; unsigned u; } v; v.f = x;
    unsigned u = v.u;
    return (ushort)((u + 0x7FFFu + ((u >> 16) & 1u)) >> 16);
}
__device__ inline unsigned umax_(unsigned a, unsigned b) { return a > b ? a : b; }
__device__ inline unsigned umin_(unsigned a, unsigned b) { return a < b ? a : b; }

__device__ inline void g2l16(const void* g, void* l) {
    __builtin_amdgcn_global_load_lds((const __attribute__((address_space(1))) unsigned int*)g,
                                     (__attribute__((address_space(3))) unsigned int*)l,
                                     16, 0, 0);
}

// Swizzled bf16 layout for 32x32x16 MFMA frags (rows x 256 ch) [verified r5/r8]:
//   byte addr = RG*16384 + p*16, p = CB*64 + hh*32 + r
//   (RG = row>>5, CB = ch>>4, hh = (ch>>3)&1, r = row&31)
// One frag (32 rows x 16 ch) = contiguous 1KB; lane l (r=l&31, hh=l>>5) at +l*16.

// ---------------------------------------------------------------------------
// Kernel 1 (fused): bid<256 -> codebook: e_n fp32, s2, swizzled Chi.
// bid>=256 -> tokens: ztn fp32, swizzled Thi. (R6-exact, known good.)
// ---------------------------------------------------------------------------
__global__ __launch_bounds__(256) void norm_pack(
        const float* __restrict__ emb, const float* __restrict__ z,
        float* __restrict__ e_n, float* __restrict__ s2,
        ushort* __restrict__ Chi,
        float* __restrict__ ztn, ushort* __restrict__ Thi) {
    __shared__ float tile[32][257];
    __shared__ float pvt[32][9];
    __shared__ float pvt2[32][9];
    __shared__ float inv[32];
    int t = threadIdx.x;
    int bid = blockIdx.x;
    if (bid < 256) {
        int k0 = bid * 32;
        int r = t >> 3, cp = t & 7;
        const float* src = emb + (size_t)(k0 + r) * C_DIM + cp * 32;
        float ss = 0.f;
        #pragma unroll
        for (int j = 0; j < 8; ++j) {
            float4 v = *(const float4*)(src + j * 4);
            tile[r][cp * 32 + j * 4 + 0] = v.x;
            tile[r][cp * 32 + j * 4 + 1] = v.y;
            tile[r][cp * 32 + j * 4 + 2] = v.z;
            tile[r][cp * 32 + j * 4 + 3] = v.w;
            ss = fmaf(v.x, v.x, ss); ss = fmaf(v.y, v.y, ss);
            ss = fmaf(v.z, v.z, ss); ss = fmaf(v.w, v.w, ss);
        }
        pvt[r][cp] = ss;
        __syncthreads();
        if (t < 32) {
            float a = 0.f;
            #pragma unroll
            for (int p = 0; p < 8; ++p) a += pvt[t][p];
            inv[t] = 1.0f / fmaxf(sqrtf(a), 1e-12f);
        }
        __syncthreads();
        float iv = inv[r];
        float s2p = 0.f;
        float* dst = e_n + (size_t)(k0 + r) * C_DIM + cp * 32;
        #pragma unroll
        for (int j = 0; j < 8; ++j) {
            float a = tile[r][cp * 32 + j * 4 + 0] * iv;
            float b = tile[r][cp * 32 + j * 4 + 1] * iv;
            float c = tile[r][cp * 32 + j * 4 + 2] * iv;
            float d = tile[r][cp * 32 + j * 4 + 3] * iv;
            s2p = fmaf(a, a, s2p); s2p = fmaf(b, b, s2p);
            s2p = fmaf(c, c, s2p); s2p = fmaf(d, d, s2p);
            float4 o = {a, b, c, d};
            *(float4*)(dst + j * 4) = o;
        }
        pvt2[r][cp] = s2p;
        __syncthreads();
        if (t < 32) {
            float a = 0.f;
            #pragma unroll
            for (int p = 0; p < 8; ++p) a += pvt2[t][p];
            s2[k0 + t] = a;
        }
        char* chiB = (char*)Chi;
        #pragma unroll
        for (int e = 0; e < 4; ++e) {
            int p = e * 256 + t;
            int row = p & 31;
            int ch0 = ((p >> 6) << 4) | (((p >> 5) & 1) << 3);
            float rv = inv[row];
            union { ushort u[8]; uint4 v; } hs;
            #pragma unroll
            for (int i = 0; i < 8; ++i)
                hs.u[i] = f32_to_bf16_rne(tile[row][ch0 + i] * rv);
            size_t addr = (size_t)bid * 16384 + (size_t)p * 16;
            *(uint4*)(chiB + addr) = hs.v;
        }
    } else {
        int tb = bid - 256;            // b*32 + h, RG = tb
        int b = tb >> 5, h = tb & 31;
        const float* zb = z + ((size_t)(b * C_DIM) * H_ + h) * W_;
        int c0 = t >> 3, wq = t & 7;
        #pragma unroll
        for (int it = 0; it < 8; ++it) {
            int c = it * 32 + c0;
            float4 v = *(const float4*)(zb + (size_t)c * HW + wq * 4);
            tile[wq * 4 + 0][c] = v.x;
            tile[wq * 4 + 1][c] = v.y;
            tile[wq * 4 + 2][c] = v.z;
            tile[wq * 4 + 3][c] = v.w;
        }
        __syncthreads();
        int part = t >> 5, w2 = t & 31;
        float s = 0.f;
        #pragma unroll
        for (int i = 0; i < 32; ++i) {
            float v = tile[w2][part * 32 + i];
            s = fmaf(v, v, s);
        }
        pvt[w2][part] = s;
        __syncthreads();
        if (t < 32) {
            float ss = 0.f;
            #pragma unroll
            for (int p = 0; p < 8; ++p) ss += pvt[t][p];
            inv[t] = 1.0f / fmaxf(sqrtf(ss), 1e-12f);
        }
        __syncthreads();
        int n_base = tb * 32;
        for (int r = 0; r < 32; ++r) {
            float val = tile[r][t] * inv[r];
            ztn[(size_t)(n_base + r) * C_DIM + t] = val;
        }
        char* thiB = (char*)Thi;
        #pragma unroll
        for (int e = 0; e < 4; ++e) {
            int p = e * 256 + t;
            int row = p & 31;
            int ch0 = ((p >> 6) << 4) | (((p >> 5) & 1) << 3);
            float rv = inv[row];
            union { ushort u[8]; uint4 v; } hs;
            #pragma unroll
            for (int i = 0; i < 8; ++i)
                hs.u[i] = f32_to_bf16_rne(tile[row][ch0 + i] * rv);
            size_t addr = (size_t)tb * 16384 + (size_t)p * 16;
            *(uint4*)(thiB + addr) = hs.v;
        }
    }
}

// ---------------------------------------------------------------------------
// Kernel 2 v7: 8-phase-style scan (T3+T4+T5 port, guide §5 template; our
// frag layout is already conflict-free so T2 swizzle is unnecessary).
// Block = 512 thr / 8 waves (2 tok-halves x 4 code-quarters), tile 256 tok x
// 512 codes (partition), K=256. Stage = 16 ch = 16KB (8 code RGs + 8 token
// RGs), RING-5 (80KB), 3 stages prefetched ahead. Per phase:
//   {6 ds_read frags | issue 2 g2l16 for stage p+3 | counted vmcnt(4/2/0) |
//    s_barrier | setprio(1) 8xMFMA setprio(0)}
// vmcnt NEVER drains to 0 mid-loop (2 loads/wave/stage x 2 ahead = 4).
// Ring-5 overwrite safety: slot (p+3)%5 last read at phase p-2, whose reads
// are lgkm-sealed before MFMA(p-2) < ds_read(p-1) < barrier(p-1) < issue(p).
// Wave acc = 2(code frag) x 4(tok frag) x f32x16 = 128 AGPR (R1-proven
// split). Top-3 extracted per 256-code subtile (pool 64 codes/source —
// strictly safer than before); merge 24 entries/token.
// ---------------------------------------------------------------------------
__global__ __launch_bounds__(512, 2) void score_topk(
        const ushort* __restrict__ Chi,
        const ushort* __restrict__ Thi, uint2* __restrict__ cand) {
    __shared__ __align__(16) char smem[81920];   // ring: 5 slots x 16KB
    int t = threadIdx.x;
    int l = t & 63, wv = t >> 6;                 // 8 waves
    int hh = l >> 5, col = l & 31;
    int wr = wv >> 2, wc = wv & 3;               // wave: 128 tok x 64 codes
    int tokBase = blockIdx.x * 256;
    int tokRG = tokBase >> 5;                    // 8 token RGs per block
    int part = blockIdx.y;
    int partBase = part * (K_CODES / KSPLIT);    // 512 codes
    int codeRGbase = partBase >> 5;              // 16 code RGs (8 per subtile)

    const char* chiB = (const char*)Chi;
    const char* thiB = (const char*)Thi;

    // ---- hoisted DMA slice table: 16 slices/stage, 2 per wave -------------
    // sl = wv*2+gi: sl<8 -> code RG sl (of current subtile); else token RG.
    // Slot-internal offset = sl<<10 for both (codes @0..8K, tokens @8K..16K).
    const char* gp[2];
    int dkt[2];                                  // delta at subtile boundary
    #pragma unroll
    for (int gi = 0; gi < 2; ++gi) {
        int sl = wv * 2 + gi;
        if (sl < 8) {
            gp[gi]  = chiB + (size_t)(codeRGbase + sl) * 16384 + (l << 4);
            dkt[gi] = 8 * 16384 - 15 * 1024;     // +8 RGs, ss 15 -> 0
        } else {
            gp[gi]  = thiB + (size_t)(tokRG + (sl - 8)) * 16384 + (l << 4);
            dkt[gi] = -15 * 1024;                // tokens re-read per subtile
        }
    }
    int ldo0 = (wv * 2 + 0) << 10, ldo1 = (wv * 2 + 1) << 10;
    int issueSlot = 0, ssIss = 0;
    auto issueStage = [&]() {
        char* base = smem + issueSlot * 16384;
        g2l16(gp[0], base + ldo0);
        g2l16(gp[1], base + ldo1);
        bool kb = (ssIss & 15) == 15;
        gp[0] += kb ? dkt[0] : 1024;
        gp[1] += kb ? dkt[1] : 1024;
        ++ssIss;
        issueSlot = (issueSlot == 4) ? 0 : issueSlot + 1;
    };

    issueStage(); issueStage(); issueStage();    // stages 0,1,2 in flight
    asm volatile("s_waitcnt vmcnt(4)" ::: "memory");   // stage 0 landed
    __builtin_amdgcn_s_barrier();

    floatx16 acc[2][4];
    #pragma unroll
    for (int n = 0; n < 2; ++n)
        #pragma unroll
        for (int m = 0; m < 4; ++m)
            #pragma unroll
            for (int r = 0; r < 16; ++r) acc[n][m][r] = 0.f;

    unsigned rv1[4] = {0u,0u,0u,0u}, rv2[4] = {0u,0u,0u,0u}, rv3[4] = {0u,0u,0u,0u};
    int ri1[4] = {0,0,0,0}, ri2[4] = {0,0,0,0}, ri3[4] = {0,0,0,0};

    int readSlot = 0;
    for (int p = 0; p < 32; ++p) {
        const char* buf = smem + readSlot * 16384;
        // this phase's fragments (slot p landed: sealed by prev vmcnt+barrier)
        short8 cf0 = *(const short8*)(buf + ((wc * 2 + 0) << 10) + (l << 4));
        short8 cf1 = *(const short8*)(buf + ((wc * 2 + 1) << 10) + (l << 4));
        short8 tf0 = *(const short8*)(buf + 8192 + ((wr * 4 + 0) << 10) + (l << 4));
        short8 tf1 = *(const short8*)(buf + 8192 + ((wr * 4 + 1) << 10) + (l << 4));
        short8 tf2 = *(const short8*)(buf + 8192 + ((wr * 4 + 2) << 10) + (l << 4));
        short8 tf3 = *(const short8*)(buf + 8192 + ((wr * 4 + 3) << 10) + (l << 4));
        if (p < 29) issueStage();                // stage p+3 -> slot (p+3)%5
        // counted wait: stage p+1 landed; leave younger stages in flight
        if (p < 29)      asm volatile("s_waitcnt vmcnt(4)" ::: "memory");
        else if (p == 29) asm volatile("s_waitcnt vmcnt(2)" ::: "memory");
        else if (p == 30) asm volatile("s_waitcnt vmcnt(0)" ::: "memory");
        __builtin_amdgcn_s_barrier();
        __builtin_amdgcn_s_setprio(1);
        acc[0][0] = __builtin_amdgcn_mfma_f32_32x32x16_bf16(cf0, tf0, acc[0][0], 0, 0, 0);
        acc[0][1] = __builtin_amdgcn_mfma_f32_32x32x16_bf16(cf0, tf1, acc[0][1], 0, 0, 0);
        acc[0][2] = __builtin_amdgcn_mfma_f32_32x32x16_bf16(cf0, tf2, acc[0][2], 0, 0, 0);
        acc[0][3] = __builtin_amdgcn_mfma_f32_32x32x16_bf16(cf0, tf3, acc[0][3], 0, 0, 0);
        acc[1][0] = __builtin_amdgcn_mfma_f32_32x32x16_bf16(cf1, tf0, acc[1][0], 0, 0, 0);
        acc[1][1] = __builtin_amdgcn_mfma_f32_32x32x16_bf16(cf1, tf1, acc[1][1], 0, 0, 0);
        acc[1][2] = __builtin_amdgcn_mfma_f32_32x32x16_bf16(cf1, tf2, acc[1][2], 0, 0, 0);
        acc[1][3] = __builtin_amdgcn_mfma_f32_32x32x16_bf16(cf1, tf3, acc[1][3], 0, 0, 0);
        __builtin_amdgcn_s_setprio(0);
        readSlot = (readSlot == 4) ? 0 : readSlot + 1;

        if ((p & 15) == 15) {                    // subtile done: extract top-3
            int kb2 = partBase + (p >> 4) * 256 + wc * 64;
            #pragma unroll
            for (int m = 0; m < 4; ++m) {
                unsigned m1 = 0u, m2 = 0u, m3 = 0u;
                #pragma unroll
                for (int n = 0; n < 2; ++n) {
                    #pragma unroll
                    for (int r = 0; r < 16; ++r) {
                        unsigned key = (__float_as_uint(fmaf(acc[n][m][r], 0.25f, 1.25f)) & 0xFFFFFFC0u)
                                       | (unsigned)((n << 4) | r);
                        unsigned t1 = umin_(m1, key); m1 = umax_(m1, key);
                        unsigned t2 = umin_(m2, t1);  m2 = umax_(m2, t1);
                        m3 = umax_(m3, t2);
                    }
                }
                unsigned mm[3] = {m1, m2, m3};
                #pragma unroll
                for (int j = 0; j < 3; ++j) {
                    unsigned k = mm[j];
                    int o = (int)(k & 63u), r = o & 15, n = o >> 4;
                    int c = kb2 + (n << 5) + (r & 3) + 8 * (r >> 2) + 4 * hh;
                    if (k > rv1[m]) {
                        rv3[m] = rv2[m]; ri3[m] = ri2[m];
                        rv2[m] = rv1[m]; ri2[m] = ri1[m];
                        rv1[m] = k; ri1[m] = c;
                    } else if (k > rv2[m]) {
                        rv3[m] = rv2[m]; ri3[m] = ri2[m];
                        rv2[m] = k; ri2[m] = c;
                    } else if (k > rv3[m]) {
                        rv3[m] = k; ri3[m] = c;
                    }
                }
            }
            #pragma unroll
            for (int n = 0; n < 2; ++n)
                #pragma unroll
                for (int m = 0; m < 4; ++m)
                    #pragma unroll
                    for (int r = 0; r < 16; ++r) acc[n][m][r] = 0.f;
        }
    }

    // merge: token tok = wr*128 + m*32 + col; 8 sources (wc x hh) x 3 each
    __syncthreads();
    unsigned* mk = (unsigned*)smem;              // [256][24] @0     (24KB)
    int*      mi = (int*)(smem + 24576);         // [256][24] @24KB  (24KB)
    #pragma unroll
    for (int m = 0; m < 4; ++m) {
        int base = (wr * 128 + m * 32 + col) * 24 + ((wc << 1) | hh) * 3;
        mk[base + 0] = rv1[m]; mi[base + 0] = ri1[m];
        mk[base + 1] = rv2[m]; mi[base + 1] = ri2[m];
        mk[base + 2] = rv3[m]; mi[base + 2] = ri3[m];
    }
    __syncthreads();
    if (t < 256) {
        unsigned b1 = 0u, b2 = 0u, b3 = 0u;
        int i1 = 0x7FFFFFFF, i2 = 0x7FFFFFFF, i3 = 0x7FFFFFFF;
        #pragma unroll
        for (int j = 0; j < 24; ++j) {
            unsigned k = mk[t * 24 + j]; int i = mi[t * 24 + j];
            if (k > b1 || (k == b1 && i < i1)) {
                b3 = b2; i3 = i2; b2 = b1; i2 = i1; b1 = k; i1 = i;
            } else if (k > b2 || (k == b2 && i < i2)) {
                b3 = b2; i3 = i2; b2 = k; i2 = i;
            } else if (k > b3 || (k == b3 && i < i3)) {
                b3 = k; i3 = i;
            }
        }
        size_t base = ((size_t)part * N_TOK + tokBase + t) * 3;
        cand[base + 0] = {b1, (unsigned)i1};
        cand[base + 1] = {b2, (unsigned)i2};
        cand[base + 2] = {b3, (unsigned)i3};
    }
}

// ---------------------------------------------------------------------------
// Kernel 3: margin-gated rescore + gather (R6-exact). Gate 2048 ULP; slow
// path rescores only candidates within 8192 ULP of the token's best key.
// ---------------------------------------------------------------------------
__global__ __launch_bounds__(256) void rescore_gather(
        const float* __restrict__ ztn, const float* __restrict__ e_n,
        const float* __restrict__ s2, const uint2* __restrict__ cand,
        float* __restrict__ out, float* __restrict__ idxf) {
    __shared__ __align__(16) char sm[32 * 257 * 4];
    __shared__ uint2 cd[32][48];
    __shared__ int idxs[32];
    __shared__ int slowlist[32];
    __shared__ unsigned bkey[32];
    __shared__ int nslow;
    float* tile = (float*)sm;        // [32][257] (phase C)
    int t = threadIdx.x;
    int bid = blockIdx.x;            // b*32 + h
    int b = bid >> 5, h = bid & 31;
    int n_base = bid * 32;
    int wv = t >> 6, l = t & 63;

    if (t == 0) nslow = 0;
    {
        int tok = t >> 3, p = t & 7;
        int n = n_base + tok;
        #pragma unroll
        for (int slot = 0; slot < 3; ++slot) {
            cd[tok][p * 3 + slot]        = cand[((size_t)p * N_TOK + n) * 3 + slot];
            cd[tok][(p + 8) * 3 + slot]  = cand[((size_t)(p + 8) * N_TOK + n) * 3 + slot];
        }
    }
    __syncthreads();

    if (t < 32) {
        unsigned b1k = 0u, b2k = 0u; int b1i = 0x7FFFFFFF, b2i = 0x7FFFFFFF;
        #pragma unroll
        for (int p = 0; p < 48; ++p) {
            uint2 c2 = cd[t][p];
            unsigned k = c2.x; int i = (int)c2.y;
            if (k > b1k || (k == b1k && i < b1i)) { b2k = b1k; b2i = b1i; b1k = k; b1i = i; }
            else if (k > b2k || (k == b2k && i < b2i)) { b2k = k; b2i = i; }
        }
        bkey[t] = b1k;
        if (b1k - b2k > 2048u) {        // scan-decided
            idxs[t] = b1i;
            idxf[n_base + t] = (float)b1i;
        } else {
            int s = atomicAdd(&nslow, 1);
            slowlist[s] = t;
        }
    }
    __syncthreads();
    int ns = nslow;
    for (int j = wv; j < ns; j += 4) {
        int tok = slowlist[j];
        int n = n_base + tok;
        unsigned bk = bkey[tok];
        float bs = FLT_MAX; int bi = 0x7FFFFFFF;
        if (l < 48) {
            uint2 c2 = cd[tok][l];
            if (c2.x + 8192u >= bk) {
                int c = (int)c2.y;
                const float* er = e_n + (size_t)c * C_DIM;
                const float* zr = ztn + (size_t)n * C_DIM;
                float s = 0.f;
                #pragma unroll
                for (int jj = 0; jj < 64; ++jj) {
                    float4 e4 = *(const float4*)(er + jj * 4);
                    float4 z4 = *(const float4*)(zr + jj * 4);
                    s = fmaf(e4.x, z4.x, s); s = fmaf(e4.y, z4.y, s);
                    s = fmaf(e4.z, z4.z, s); s = fmaf(e4.w, z4.w, s);
                }
                bs = s2[c] - 2.f * s;
                bi = c;
            }
        }
        #pragma unroll
        for (int d = 1; d < 64; d <<= 1) {
            float os = __shfl_xor(bs, d);
            int   oi = __shfl_xor(bi, d);
            if (os < bs || (os == bs && oi < bi)) { bs = os; bi = oi; }
        }
        if (l == 0) { idxs[tok] = bi; idxf[n] = (float)bi; }
    }
    __syncthreads();

    for (int r = 0; r < 32; ++r) {
        int k = idxs[r];
        tile[r * 257 + t] = e_n[(size_t)k * C_DIM + t];
    }
    __syncthreads();
    int w = t & 31, c0 = t >> 5;
    float* ob = out + ((size_t)(b * C_DIM) * H_ + h) * W_;
    #pragma unroll
    for (int it = 0; it < 32; ++it) {
        int c = it * 8 + c0;
        ob[(size_t)c * HW + w] = tile[w * 257 + c];
    }
}

// ---------------------------------------------------------------------------
extern "C" void kernel_launch(void* const* d_in, const int* in_sizes, int n_in,
                              void* d_out, int out_size, void* d_ws, size_t ws_size,
                              hipStream_t stream) {
    const float* z   = (const float*)d_in[0];
    const float* emb = (const float*)d_in[1];
    float* out  = (float*)d_out;
    float* idxf = out + (size_t)B_ * C_DIM * H_ * W_;

    char* ws = (char*)d_ws;
    size_t o = 0;
    float*  e_n  = (float*)(ws + o);  o += (size_t)K_CODES * C_DIM * 4;   // 8 MB
    float*  s2   = (float*)(ws + o);  o += 32768;
    float*  ztn  = (float*)(ws + o);  o += (size_t)N_TOK * C_DIM * 4;     // 16 MB
    ushort* Chi  = (ushort*)(ws + o); o += (size_t)K_CODES * C_DIM * 2;   // 4 MB
    ushort* Thi  = (ushort*)(ws + o); o += (size_t)N_TOK * C_DIM * 2;     // 8 MB
    uint2*  cand = (uint2*)(ws + o);  o += (size_t)KSPLIT * N_TOK * 3 * 8; // 6 MB

    hipLaunchKernelGGL(norm_pack, dim3(256 + B_ * H_), dim3(256), 0, stream,
                       emb, z, e_n, s2, Chi, ztn, Thi);
    hipLaunchKernelGGL(score_topk, dim3(N_TOK / 256, KSPLIT), dim3(512), 0, stream,
                       Chi, Thi, cand);
    hipLaunchKernelGGL(rescore_gather, dim3(B_ * H_), dim3(256), 0, stream,
                       ztn, e_n, s2, cand, out, idxf);
}

// Round 10
// 203.359 us; speedup vs baseline: 1.0530x; 1.0530x over previous
//
#include <hip/hip_runtime.h>
#include <math.h>
#include <float.h>

#define K_CODES 8192
#define C_DIM   256
#define N_TOK   16384
#define B_      16
#define H_      32
#define W_      32
#define HW      1024
#define KSPLIT  16
#define TOKS_PER_BLK 256

typedef short  short8   __attribute__((ext_vector_type(8)));
typedef float  floatx16 __attribute__((ext_vector_type(16)));

__device__ inline ushort f32_to_bf16_rne(float x) {
    union { float f; unsigned u; } v; v.f = x;
    unsigned u = v.u;
    return (ushort)((u + 0x7FFFu + ((u >> 16) & 1u)) >> 16);
}
__device__ inline unsigned umax_(unsigned a, unsigned b) { return a > b ? a : b; }
__device__ inline unsigned umin_(unsigned a, unsigned b) { return a < b ? a : b; }

__device__ inline void g2l16(const void* g, void* l) {
    __builtin_amdgcn_global_load_lds((const __attribute__((address_space(1))) unsigned int*)g,
                                     (__attribute__((address_space(3))) unsigned int*)l,
                                     16, 0, 0);
}

// Swizzled bf16 layout for 32x32x16 MFMA frags (rows x 256 ch) [verified r5/r8]:
//   byte addr = RG*16384 + p*16, p = CB*64 + hh*32 + r
//   (RG = row>>5, CB = ch>>4, hh = (ch>>3)&1, r = row&31)
// One frag (32 rows x 16 ch) = contiguous 1KB; lane l (r=l&31, hh=l>>5) at +l*16.

// ---------------------------------------------------------------------------
// Kernel 1 (fused, R6-exact): bid<256 -> codebook: e_n fp32, s2, swizzled
// Chi. bid>=256 -> tokens: ztn fp32, swizzled Thi. z loads float4 (G13).
// ---------------------------------------------------------------------------
__global__ __launch_bounds__(256) void norm_pack(
        const float* __restrict__ emb, const float* __restrict__ z,
        float* __restrict__ e_n, float* __restrict__ s2,
        ushort* __restrict__ Chi,
        float* __restrict__ ztn, ushort* __restrict__ Thi) {
    __shared__ float tile[32][257];
    __shared__ float pvt[32][9];
    __shared__ float pvt2[32][9];
    __shared__ float inv[32];
    int t = threadIdx.x;
    int bid = blockIdx.x;
    if (bid < 256) {
        int k0 = bid * 32;
        int r = t >> 3, cp = t & 7;
        const float* src = emb + (size_t)(k0 + r) * C_DIM + cp * 32;
        float ss = 0.f;
        #pragma unroll
        for (int j = 0; j < 8; ++j) {
            float4 v = *(const float4*)(src + j * 4);
            tile[r][cp * 32 + j * 4 + 0] = v.x;
            tile[r][cp * 32 + j * 4 + 1] = v.y;
            tile[r][cp * 32 + j * 4 + 2] = v.z;
            tile[r][cp * 32 + j * 4 + 3] = v.w;
            ss = fmaf(v.x, v.x, ss); ss = fmaf(v.y, v.y, ss);
            ss = fmaf(v.z, v.z, ss); ss = fmaf(v.w, v.w, ss);
        }
        pvt[r][cp] = ss;
        __syncthreads();
        if (t < 32) {
            float a = 0.f;
            #pragma unroll
            for (int p = 0; p < 8; ++p) a += pvt[t][p];
            inv[t] = 1.0f / fmaxf(sqrtf(a), 1e-12f);
        }
        __syncthreads();
        float iv = inv[r];
        float s2p = 0.f;
        float* dst = e_n + (size_t)(k0 + r) * C_DIM + cp * 32;
        #pragma unroll
        for (int j = 0; j < 8; ++j) {
            float a = tile[r][cp * 32 + j * 4 + 0] * iv;
            float b = tile[r][cp * 32 + j * 4 + 1] * iv;
            float c = tile[r][cp * 32 + j * 4 + 2] * iv;
            float d = tile[r][cp * 32 + j * 4 + 3] * iv;
            s2p = fmaf(a, a, s2p); s2p = fmaf(b, b, s2p);
            s2p = fmaf(c, c, s2p); s2p = fmaf(d, d, s2p);
            float4 o = {a, b, c, d};
            *(float4*)(dst + j * 4) = o;
        }
        pvt2[r][cp] = s2p;
        __syncthreads();
        if (t < 32) {
            float a = 0.f;
            #pragma unroll
            for (int p = 0; p < 8; ++p) a += pvt2[t][p];
            s2[k0 + t] = a;
        }
        char* chiB = (char*)Chi;
        #pragma unroll
        for (int e = 0; e < 4; ++e) {
            int p = e * 256 + t;
            int row = p & 31;
            int ch0 = ((p >> 6) << 4) | (((p >> 5) & 1) << 3);
            float rv = inv[row];
            union { ushort u[8]; uint4 v; } hs;
            #pragma unroll
            for (int i = 0; i < 8; ++i)
                hs.u[i] = f32_to_bf16_rne(tile[row][ch0 + i] * rv);
            size_t addr = (size_t)bid * 16384 + (size_t)p * 16;
            *(uint4*)(chiB + addr) = hs.v;
        }
    } else {
        int tb = bid - 256;            // b*32 + h, RG = tb
        int b = tb >> 5, h = tb & 31;
        const float* zb = z + ((size_t)(b * C_DIM) * H_ + h) * W_;
        int c0 = t >> 3, wq = t & 7;
        #pragma unroll
        for (int it = 0; it < 8; ++it) {
            int c = it * 32 + c0;
            float4 v = *(const float4*)(zb + (size_t)c * HW + wq * 4);
            tile[wq * 4 + 0][c] = v.x;
            tile[wq * 4 + 1][c] = v.y;
            tile[wq * 4 + 2][c] = v.z;
            tile[wq * 4 + 3][c] = v.w;
        }
        __syncthreads();
        int part = t >> 5, w2 = t & 31;
        float s = 0.f;
        #pragma unroll
        for (int i = 0; i < 32; ++i) {
            float v = tile[w2][part * 32 + i];
            s = fmaf(v, v, s);
        }
        pvt[w2][part] = s;
        __syncthreads();
        if (t < 32) {
            float ss = 0.f;
            #pragma unroll
            for (int p = 0; p < 8; ++p) ss += pvt[t][p];
            inv[t] = 1.0f / fmaxf(sqrtf(ss), 1e-12f);
        }
        __syncthreads();
        int n_base = tb * 32;
        for (int r = 0; r < 32; ++r) {
            float val = tile[r][t] * inv[r];
            ztn[(size_t)(n_base + r) * C_DIM + t] = val;
        }
        char* thiB = (char*)Thi;
        #pragma unroll
        for (int e = 0; e < 4; ++e) {
            int p = e * 256 + t;
            int row = p & 31;
            int ch0 = ((p >> 6) << 4) | (((p >> 5) & 1) << 3);
            float rv = inv[row];
            union { ushort u[8]; uint4 v; } hs;
            #pragma unroll
            for (int i = 0; i < 8; ++i)
                hs.u[i] = f32_to_bf16_rne(tile[row][ch0 + i] * rv);
            size_t addr = (size_t)tb * 16384 + (size_t)p * 16;
            *(uint4*)(thiB + addr) = hs.v;
        }
    }
}

// ---------------------------------------------------------------------------
// Kernel 2 (R6-exact, proven best): MFMA scan, 32x32x16 bf16, single-product
// (c_hi*t_hi). Ping-pong: stage = 16 ch = 12KB (codes 4KB + tokens 8KB),
// dbuf 24KB, ONE barrier/stage. 4 waves; tile 256 tok x 128 codes; wave =
// 64 tok x 128 codes (CT=4, NT=2, acc 128 AGPR). Pipes measured to sum:
// matrix 65K + VALU 83K + LDS 72K cyc/SIMD = runtime; occupancy capped at
// 2 waves/SIMD (reg band), 5 restructures failed to beat this — kept as-is.
// ---------------------------------------------------------------------------
__global__ __launch_bounds__(256, 2) void score_topk(
        const ushort* __restrict__ Chi,
        const ushort* __restrict__ Thi, uint2* __restrict__ cand) {
    __shared__ __align__(16) char smem[24576];   // buf0 @0, buf1 @12288
    int t = threadIdx.x;
    int l = t & 63, wv = t >> 6;
    int hh = l >> 5, col = l & 31;
    int tokBase = blockIdx.x * TOKS_PER_BLK;
    int tokRG = tokBase >> 5;                // 8 token RG32s per block
    int part = blockIdx.y;
    int partBase = part * (K_CODES / KSPLIT);   // 512 codes per partition
    int codeRGbase = partBase >> 5;

    const char* chiB = (const char*)Chi;
    const char* thiB = (const char*)Thi;

    unsigned rv1[2] = {0u, 0u}, rv2[2] = {0u, 0u}, rv3[2] = {0u, 0u};
    int ri1[2] = {0, 0}, ri2[2] = {0, 0}, ri3[2] = {0, 0};

    // stage(kt, s) -> buf: 12 slices of 1KB, 3 per wave
    auto stage = [&](int skt, int ss, char* buf) {
        int codeRG = codeRGbase + skt * 4;
        #pragma unroll
        for (int gi = 0; gi < 3; ++gi) {
            int slice = wv * 3 + gi;
            const char* gb;
            int off;
            if (slice < 4) {
                gb = chiB + (size_t)(codeRG + slice) * 16384;
                off = slice << 10;
            } else {
                int trg = slice - 4;
                gb = thiB + (size_t)(tokRG + trg) * 16384;
                off = 4096 + (trg << 10);
            }
            g2l16(gb + ss * 1024 + (l << 4), buf + off);
        }
    };

    stage(0, 0, smem);                       // prologue into buf0

    for (int kt = 0; kt < 4; ++kt) {
        floatx16 acc[4][2];
        #pragma unroll
        for (int ct = 0; ct < 4; ++ct)
            #pragma unroll
            for (int nt = 0; nt < 2; ++nt)
                #pragma unroll
                for (int r = 0; r < 16; ++r) acc[ct][nt][r] = 0.f;

        for (int s = 0; s < 16; ++s) {
            int gidx = kt * 16 + s;
            __syncthreads();                 // current buf ready; prev readers done
            int nidx = gidx + 1;
            if (nidx < 64)
                stage(nidx >> 4, nidx & 15, smem + ((nidx & 1) ? 12288 : 0));
            const char* buf = smem + ((gidx & 1) ? 12288 : 0);

            short8 bh[2];
            #pragma unroll
            for (int nt = 0; nt < 2; ++nt) {
                int trg = wv * 2 + nt;
                bh[nt] = *(const short8*)(buf + 4096 + (trg << 10) + (l << 4));
            }
            #pragma unroll
            for (int ct = 0; ct < 4; ++ct) {
                short8 ah = *(const short8*)(buf + (ct << 10) + (l << 4));
                #pragma unroll
                for (int nt = 0; nt < 2; ++nt) {
                    acc[ct][nt] = __builtin_amdgcn_mfma_f32_32x32x16_bf16(ah, bh[nt], acc[ct][nt], 0, 0, 0);
                }
            }
        }

        // packed-key top-3. key = (bits(d*0.25+1.25) & ~63) | (ct<<4 | reg)
        int kbase = partBase + kt * 128;
        #pragma unroll
        for (int nt = 0; nt < 2; ++nt) {
            unsigned m1 = 0u, m2 = 0u, m3 = 0u;
            #pragma unroll
            for (int ct = 0; ct < 4; ++ct) {
                #pragma unroll
                for (int r = 0; r < 16; ++r) {
                    unsigned key = (__float_as_uint(fmaf(acc[ct][nt][r], 0.25f, 1.25f)) & 0xFFFFFFC0u)
                                   | (unsigned)((ct << 4) | r);
                    unsigned t1 = umin_(m1, key); m1 = umax_(m1, key);
                    unsigned t2 = umin_(m2, t1);  m2 = umax_(m2, t1);
                    m3 = umax_(m3, t2);
                }
            }
            unsigned mm[3] = {m1, m2, m3};
            #pragma unroll
            for (int j = 0; j < 3; ++j) {
                unsigned k = mm[j];
                int o = (int)(k & 63u), r = o & 15;
                int c = kbase + ((o >> 4) << 5) + (r & 3) + 8 * (r >> 2) + 4 * hh;
                if (k > rv1[nt]) {
                    rv3[nt] = rv2[nt]; ri3[nt] = ri2[nt];
                    rv2[nt] = rv1[nt]; ri2[nt] = ri1[nt];
                    rv1[nt] = k; ri1[nt] = c;
                } else if (k > rv2[nt]) {
                    rv3[nt] = rv2[nt]; ri3[nt] = ri2[nt];
                    rv2[nt] = k; ri2[nt] = c;
                } else if (k > rv3[nt]) {
                    rv3[nt] = k; ri3[nt] = c;
                }
            }
        }
    }

    // merge across the 2 lane-halves per token (token = wv*64 + nt*32 + col)
    __syncthreads();
    unsigned* mk = (unsigned*)smem;              // [256][6]
    int*      mi = (int*)(smem + 8192);
    #pragma unroll
    for (int nt = 0; nt < 2; ++nt) {
        int base = (wv * 64 + nt * 32 + col) * 6 + hh * 3;
        mk[base + 0] = rv1[nt]; mi[base + 0] = ri1[nt];
        mk[base + 1] = rv2[nt]; mi[base + 1] = ri2[nt];
        mk[base + 2] = rv3[nt]; mi[base + 2] = ri3[nt];
    }
    __syncthreads();
    {
        unsigned b1 = 0u, b2 = 0u, b3 = 0u;
        int i1 = 0x7FFFFFFF, i2 = 0x7FFFFFFF, i3 = 0x7FFFFFFF;
        #pragma unroll
        for (int j = 0; j < 6; ++j) {
            unsigned k = mk[t * 6 + j]; int i = mi[t * 6 + j];
            if (k > b1 || (k == b1 && i < i1)) {
                b3 = b2; i3 = i2; b2 = b1; i2 = i1; b1 = k; i1 = i;
            } else if (k > b2 || (k == b2 && i < i2)) {
                b3 = b2; i3 = i2; b2 = k; i2 = i;
            } else if (k > b3 || (k == b3 && i < i3)) {
                b3 = k; i3 = i;
            }
        }
        size_t base = ((size_t)part * N_TOK + tokBase + t) * 3;
        cand[base + 0] = {b1, (unsigned)i1};
        cand[base + 1] = {b2, (unsigned)i2};
        cand[base + 2] = {b3, (unsigned)i3};
    }
}

// ---------------------------------------------------------------------------
// Kernel 3a: decide + rescore only (no gather). 256 tokens/block (64 blocks):
// thread-per-token merge of 48 (key,idx) from global; gate 2048 ULP; slow
// tokens pooled block-wide (load-balanced over 4 waves, ~256x less skew than
// the old 32-token blocks). Slow path re-reads cand from global (8B/lane),
// rescores only candidates within 8192 ULP of best. Writes idxf only.
// ---------------------------------------------------------------------------
__global__ __launch_bounds__(256) void decide_rescore(
        const float* __restrict__ ztn, const float* __restrict__ e_n,
        const float* __restrict__ s2, const uint2* __restrict__ cand,
        float* __restrict__ idxf) {
    __shared__ int slowlist[256];
    __shared__ unsigned slowbk[256];
    __shared__ int nslow;
    int t = threadIdx.x;
    int n0 = blockIdx.x * 256;
    int wv = t >> 6, l = t & 63;
    if (t == 0) nslow = 0;
    __syncthreads();
    {
        int n = n0 + t;
        unsigned b1k = 0u, b2k = 0u; int b1i = 0x7FFFFFFF, b2i = 0x7FFFFFFF;
        for (int p = 0; p < 16; ++p) {
            #pragma unroll
            for (int s = 0; s < 3; ++s) {
                uint2 c2 = cand[((size_t)p * N_TOK + n) * 3 + s];
                unsigned k = c2.x; int i = (int)c2.y;
                if (k > b1k || (k == b1k && i < b1i)) { b2k = b1k; b2i = b1i; b1k = k; b1i = i; }
                else if (k > b2k || (k == b2k && i < b2i)) { b2k = k; b2i = i; }
            }
        }
        if (b1k - b2k > 2048u) {
            idxf[n] = (float)b1i;
        } else {
            int s = atomicAdd(&nslow, 1);
            slowlist[s] = t; slowbk[s] = b1k;
        }
    }
    __syncthreads();
    int ns = nslow;
    for (int j = wv; j < ns; j += 4) {
        int tok = slowlist[j];
        int n = n0 + tok;
        unsigned bk = slowbk[j];
        float bs = FLT_MAX; int bi = 0x7FFFFFFF;
        if (l < 48) {
            int p = l / 3, s = l - p * 3;
            uint2 c2 = cand[((size_t)p * N_TOK + n) * 3 + s];
            if (c2.x + 8192u >= bk) {
                int c = (int)c2.y;
                const float* er = e_n + (size_t)c * C_DIM;
                const float* zr = ztn + (size_t)n * C_DIM;
                float sdot = 0.f;
                #pragma unroll
                for (int jj = 0; jj < 64; ++jj) {
                    float4 e4 = *(const float4*)(er + jj * 4);
                    float4 z4 = *(const float4*)(zr + jj * 4);
                    sdot = fmaf(e4.x, z4.x, sdot); sdot = fmaf(e4.y, z4.y, sdot);
                    sdot = fmaf(e4.z, z4.z, sdot); sdot = fmaf(e4.w, z4.w, sdot);
                }
                bs = s2[c] - 2.f * sdot;
                bi = c;
            }
        }
        #pragma unroll
        for (int d = 1; d < 64; d <<= 1) {
            float os = __shfl_xor(bs, d);
            int   oi = __shfl_xor(bi, d);
            if (os < bs || (os == bs && oi < bi)) { bs = os; bi = oi; }
        }
        if (l == 0) idxf[n] = (float)bi;
    }
}

// ---------------------------------------------------------------------------
// Kernel 3b: pure gather + transpose-write (BW-bound, no serialization).
// Block per (b,h) = 32 tokens; reads idx from idxf (exact small ints).
// ---------------------------------------------------------------------------
__global__ __launch_bounds__(256) void gather_out(
        const float* __restrict__ e_n, const float* __restrict__ idxf,
        float* __restrict__ out) {
    __shared__ float tile[32 * 257];
    int t = threadIdx.x;
    int bid = blockIdx.x;            // b*32 + h
    int b = bid >> 5, h = bid & 31;
    int n_base = bid * 32;
    for (int r = 0; r < 32; ++r) {
        int k = (int)idxf[n_base + r];
        tile[r * 257 + t] = e_n[(size_t)k * C_DIM + t];
    }
    __syncthreads();
    int w = t & 31, c0 = t >> 5;
    float* ob = out + ((size_t)(b * C_DIM) * H_ + h) * W_;
    #pragma unroll
    for (int it = 0; it < 32; ++it) {
        int c = it * 8 + c0;
        ob[(size_t)c * HW + w] = tile[w * 257 + c];
    }
}

// ---------------------------------------------------------------------------
extern "C" void kernel_launch(void* const* d_in, const int* in_sizes, int n_in,
                              void* d_out, int out_size, void* d_ws, size_t ws_size,
                              hipStream_t stream) {
    const float* z   = (const float*)d_in[0];
    const float* emb = (const float*)d_in[1];
    float* out  = (float*)d_out;
    float* idxf = out + (size_t)B_ * C_DIM * H_ * W_;

    char* ws = (char*)d_ws;
    size_t o = 0;
    float*  e_n  = (float*)(ws + o);  o += (size_t)K_CODES * C_DIM * 4;   // 8 MB
    float*  s2   = (float*)(ws + o);  o += 32768;
    float*  ztn  = (float*)(ws + o);  o += (size_t)N_TOK * C_DIM * 4;     // 16 MB
    ushort* Chi  = (ushort*)(ws + o); o += (size_t)K_CODES * C_DIM * 2;   // 4 MB
    ushort* Thi  = (ushort*)(ws + o); o += (size_t)N_TOK * C_DIM * 2;     // 8 MB
    uint2*  cand = (uint2*)(ws + o);  o += (size_t)KSPLIT * N_TOK * 3 * 8; // 6 MB

    hipLaunchKernelGGL(norm_pack, dim3(256 + B_ * H_), dim3(256), 0, stream,
                       emb, z, e_n, s2, Chi, ztn, Thi);
    hipLaunchKernelGGL(score_topk, dim3(N_TOK / TOKS_PER_BLK, KSPLIT), dim3(256), 0, stream,
                       Chi, Thi, cand);
    hipLaunchKernelGGL(decide_rescore, dim3(N_TOK / 256), dim3(256), 0, stream,
                       ztn, e_n, s2, cand, idxf);
    hipLaunchKernelGGL(gather_out, dim3(B_ * H_), dim3(256), 0, stream,
                       e_n, idxf, out);
}

// Round 11
// 172.684 us; speedup vs baseline: 1.2401x; 1.1776x over previous
//
#include <hip/hip_runtime.h>
#include <math.h>
#include <float.h>

#define K_CODES 8192
#define C_DIM   256
#define N_TOK   16384
#define B_      16
#define H_      32
#define W_      32
#define HW      1024
#define KSPLIT  8
#define TOKS_PER_BLK 256

typedef short  short8   __attribute__((ext_vector_type(8)));
typedef float  floatx16 __attribute__((ext_vector_type(16)));

__device__ inline ushort f32_to_bf16_rne(float x) {
    union { float f; unsigned u; } v; v.f = x;
    unsigned u = v.u;
    return (ushort)((u + 0x7FFFu + ((u >> 16) & 1u)) >> 16);
}
__device__ inline unsigned umax_(unsigned a, unsigned b) { return a > b ? a : b; }
__device__ inline unsigned umin_(unsigned a, unsigned b) { return a < b ? a : b; }

__device__ inline void g2l16(const void* g, void* l) {
    __builtin_amdgcn_global_load_lds((const __attribute__((address_space(1))) unsigned int*)g,
                                     (__attribute__((address_space(3))) unsigned int*)l,
                                     16, 0, 0);
}

// Swizzled bf16 layout for 32x32x16 MFMA frags (rows x 256 ch) [verified r5/r8]:
//   byte addr = RG*16384 + p*16, p = CB*64 + hh*32 + r
//   (RG = row>>5, CB = ch>>4, hh = (ch>>3)&1, r = row&31)
// One frag (32 rows x 16 ch) = contiguous 1KB; lane l (r=l&31, hh=l>>5) at +l*16.

// ---------------------------------------------------------------------------
// Kernel 1 (fused, R6-exact): bid<256 -> codebook: e_n fp32, s2, swizzled
// Chi. bid>=256 -> tokens: ztn fp32, swizzled Thi. z loads float4 (G13).
// ---------------------------------------------------------------------------
__global__ __launch_bounds__(256) void norm_pack(
        const float* __restrict__ emb, const float* __restrict__ z,
        float* __restrict__ e_n, float* __restrict__ s2,
        ushort* __restrict__ Chi,
        float* __restrict__ ztn, ushort* __restrict__ Thi) {
    __shared__ float tile[32][257];
    __shared__ float pvt[32][9];
    __shared__ float pvt2[32][9];
    __shared__ float inv[32];
    int t = threadIdx.x;
    int bid = blockIdx.x;
    if (bid < 256) {
        int k0 = bid * 32;
        int r = t >> 3, cp = t & 7;
        const float* src = emb + (size_t)(k0 + r) * C_DIM + cp * 32;
        float ss = 0.f;
        #pragma unroll
        for (int j = 0; j < 8; ++j) {
            float4 v = *(const float4*)(src + j * 4);
            tile[r][cp * 32 + j * 4 + 0] = v.x;
            tile[r][cp * 32 + j * 4 + 1] = v.y;
            tile[r][cp * 32 + j * 4 + 2] = v.z;
            tile[r][cp * 32 + j * 4 + 3] = v.w;
            ss = fmaf(v.x, v.x, ss); ss = fmaf(v.y, v.y, ss);
            ss = fmaf(v.z, v.z, ss); ss = fmaf(v.w, v.w, ss);
        }
        pvt[r][cp] = ss;
        __syncthreads();
        if (t < 32) {
            float a = 0.f;
            #pragma unroll
            for (int p = 0; p < 8; ++p) a += pvt[t][p];
            inv[t] = 1.0f / fmaxf(sqrtf(a), 1e-12f);
        }
        __syncthreads();
        float iv = inv[r];
        float s2p = 0.f;
        float* dst = e_n + (size_t)(k0 + r) * C_DIM + cp * 32;
        #pragma unroll
        for (int j = 0; j < 8; ++j) {
            float a = tile[r][cp * 32 + j * 4 + 0] * iv;
            float b = tile[r][cp * 32 + j * 4 + 1] * iv;
            float c = tile[r][cp * 32 + j * 4 + 2] * iv;
            float d = tile[r][cp * 32 + j * 4 + 3] * iv;
            s2p = fmaf(a, a, s2p); s2p = fmaf(b, b, s2p);
            s2p = fmaf(c, c, s2p); s2p = fmaf(d, d, s2p);
            float4 o = {a, b, c, d};
            *(float4*)(dst + j * 4) = o;
        }
        pvt2[r][cp] = s2p;
        __syncthreads();
        if (t < 32) {
            float a = 0.f;
            #pragma unroll
            for (int p = 0; p < 8; ++p) a += pvt2[t][p];
            s2[k0 + t] = a;
        }
        char* chiB = (char*)Chi;
        #pragma unroll
        for (int e = 0; e < 4; ++e) {
            int p = e * 256 + t;
            int row = p & 31;
            int ch0 = ((p >> 6) << 4) | (((p >> 5) & 1) << 3);
            float rv = inv[row];
            union { ushort u[8]; uint4 v; } hs;
            #pragma unroll
            for (int i = 0; i < 8; ++i)
                hs.u[i] = f32_to_bf16_rne(tile[row][ch0 + i] * rv);
            size_t addr = (size_t)bid * 16384 + (size_t)p * 16;
            *(uint4*)(chiB + addr) = hs.v;
        }
    } else {
        int tb = bid - 256;            // b*32 + h, RG = tb
        int b = tb >> 5, h = tb & 31;
        const float* zb = z + ((size_t)(b * C_DIM) * H_ + h) * W_;
        int c0 = t >> 3, wq = t & 7;
        #pragma unroll
        for (int it = 0; it < 8; ++it) {
            int c = it * 32 + c0;
            float4 v = *(const float4*)(zb + (size_t)c * HW + wq * 4);
            tile[wq * 4 + 0][c] = v.x;
            tile[wq * 4 + 1][c] = v.y;
            tile[wq * 4 + 2][c] = v.z;
            tile[wq * 4 + 3][c] = v.w;
        }
        __syncthreads();
        int part = t >> 5, w2 = t & 31;
        float s = 0.f;
        #pragma unroll
        for (int i = 0; i < 32; ++i) {
            float v = tile[w2][part * 32 + i];
            s = fmaf(v, v, s);
        }
        pvt[w2][part] = s;
        __syncthreads();
        if (t < 32) {
            float ss = 0.f;
            #pragma unroll
            for (int p = 0; p < 8; ++p) ss += pvt[t][p];
            inv[t] = 1.0f / fmaxf(sqrtf(ss), 1e-12f);
        }
        __syncthreads();
        int n_base = tb * 32;
        for (int r = 0; r < 32; ++r) {
            float val = tile[r][t] * inv[r];
            ztn[(size_t)(n_base + r) * C_DIM + t] = val;
        }
        char* thiB = (char*)Thi;
        #pragma unroll
        for (int e = 0; e < 4; ++e) {
            int p = e * 256 + t;
            int row = p & 31;
            int ch0 = ((p >> 6) << 4) | (((p >> 5) & 1) << 3);
            float rv = inv[row];
            union { ushort u[8]; uint4 v; } hs;
            #pragma unroll
            for (int i = 0; i < 8; ++i)
                hs.u[i] = f32_to_bf16_rne(tile[row][ch0 + i] * rv);
            size_t addr = (size_t)tb * 16384 + (size_t)p * 16;
            *(uint4*)(thiB + addr) = hs.v;
        }
    }
}

// ---------------------------------------------------------------------------
// Kernel 2 (R6 structure, KSPLIT=8): MFMA scan, 32x32x16 bf16, single-product
// (c_hi*t_hi). Partition = 1024 codes, 8 kt of 128 codes each; grid 64x8 =
// 512 blocks = exactly 2/CU resident (single occupancy pass, no 2nd-wave
// tail). Ping-pong: stage = 16 ch = 12KB (codes 4KB + tokens 8KB), dbuf
// 24KB, ONE barrier/stage. 4 waves; wave = 64 tok x 128 codes (CT=4, NT=2,
// acc 128 AGPR). Candidate-collection proof is partition-count-independent
// (any non-collected code's key <= its partition's 3rd key <= global b2k),
// so decisions — and absmax — are identical to KSPLIT=16.
// ---------------------------------------------------------------------------
__global__ __launch_bounds__(256, 2) void score_topk(
        const ushort* __restrict__ Chi,
        const ushort* __restrict__ Thi, uint2* __restrict__ cand) {
    __shared__ __align__(16) char smem[24576];   // buf0 @0, buf1 @12288
    int t = threadIdx.x;
    int l = t & 63, wv = t >> 6;
    int hh = l >> 5, col = l & 31;
    int tokBase = blockIdx.x * TOKS_PER_BLK;
    int tokRG = tokBase >> 5;                // 8 token RG32s per block
    int part = blockIdx.y;
    int partBase = part * (K_CODES / KSPLIT);   // 1024 codes per partition
    int codeRGbase = partBase >> 5;          // 32 code RGs per partition

    const char* chiB = (const char*)Chi;
    const char* thiB = (const char*)Thi;

    unsigned rv1[2] = {0u, 0u}, rv2[2] = {0u, 0u}, rv3[2] = {0u, 0u};
    int ri1[2] = {0, 0}, ri2[2] = {0, 0}, ri3[2] = {0, 0};

    // stage(kt, s) -> buf: 12 slices of 1KB, 3 per wave
    auto stage = [&](int skt, int ss, char* buf) {
        int codeRG = codeRGbase + skt * 4;
        #pragma unroll
        for (int gi = 0; gi < 3; ++gi) {
            int slice = wv * 3 + gi;
            const char* gb;
            int off;
            if (slice < 4) {
                gb = chiB + (size_t)(codeRG + slice) * 16384;
                off = slice << 10;
            } else {
                int trg = slice - 4;
                gb = thiB + (size_t)(tokRG + trg) * 16384;
                off = 4096 + (trg << 10);
            }
            g2l16(gb + ss * 1024 + (l << 4), buf + off);
        }
    };

    stage(0, 0, smem);                       // prologue into buf0

    for (int kt = 0; kt < 8; ++kt) {
        floatx16 acc[4][2];
        #pragma unroll
        for (int ct = 0; ct < 4; ++ct)
            #pragma unroll
            for (int nt = 0; nt < 2; ++nt)
                #pragma unroll
                for (int r = 0; r < 16; ++r) acc[ct][nt][r] = 0.f;

        for (int s = 0; s < 16; ++s) {
            int gidx = kt * 16 + s;
            __syncthreads();                 // current buf ready; prev readers done
            int nidx = gidx + 1;
            if (nidx < 128)
                stage(nidx >> 4, nidx & 15, smem + ((nidx & 1) ? 12288 : 0));
            const char* buf = smem + ((gidx & 1) ? 12288 : 0);

            short8 bh[2];
            #pragma unroll
            for (int nt = 0; nt < 2; ++nt) {
                int trg = wv * 2 + nt;
                bh[nt] = *(const short8*)(buf + 4096 + (trg << 10) + (l << 4));
            }
            #pragma unroll
            for (int ct = 0; ct < 4; ++ct) {
                short8 ah = *(const short8*)(buf + (ct << 10) + (l << 4));
                #pragma unroll
                for (int nt = 0; nt < 2; ++nt) {
                    acc[ct][nt] = __builtin_amdgcn_mfma_f32_32x32x16_bf16(ah, bh[nt], acc[ct][nt], 0, 0, 0);
                }
            }
        }

        // packed-key top-3. key = (bits(d*0.25+1.25) & ~63) | (ct<<4 | reg)
        int kbase = partBase + kt * 128;
        #pragma unroll
        for (int nt = 0; nt < 2; ++nt) {
            unsigned m1 = 0u, m2 = 0u, m3 = 0u;
            #pragma unroll
            for (int ct = 0; ct < 4; ++ct) {
                #pragma unroll
                for (int r = 0; r < 16; ++r) {
                    unsigned key = (__float_as_uint(fmaf(acc[ct][nt][r], 0.25f, 1.25f)) & 0xFFFFFFC0u)
                                   | (unsigned)((ct << 4) | r);
                    unsigned t1 = umin_(m1, key); m1 = umax_(m1, key);
                    unsigned t2 = umin_(m2, t1);  m2 = umax_(m2, t1);
                    m3 = umax_(m3, t2);
                }
            }
            unsigned mm[3] = {m1, m2, m3};
            #pragma unroll
            for (int j = 0; j < 3; ++j) {
                unsigned k = mm[j];
                int o = (int)(k & 63u), r = o & 15;
                int c = kbase + ((o >> 4) << 5) + (r & 3) + 8 * (r >> 2) + 4 * hh;
                if (k > rv1[nt]) {
                    rv3[nt] = rv2[nt]; ri3[nt] = ri2[nt];
                    rv2[nt] = rv1[nt]; ri2[nt] = ri1[nt];
                    rv1[nt] = k; ri1[nt] = c;
                } else if (k > rv2[nt]) {
                    rv3[nt] = rv2[nt]; ri3[nt] = ri2[nt];
                    rv2[nt] = k; ri2[nt] = c;
                } else if (k > rv3[nt]) {
                    rv3[nt] = k; ri3[nt] = c;
                }
            }
        }
    }

    // merge across the 2 lane-halves per token (token = wv*64 + nt*32 + col)
    __syncthreads();
    unsigned* mk = (unsigned*)smem;              // [256][6]
    int*      mi = (int*)(smem + 8192);
    #pragma unroll
    for (int nt = 0; nt < 2; ++nt) {
        int base = (wv * 64 + nt * 32 + col) * 6 + hh * 3;
        mk[base + 0] = rv1[nt]; mi[base + 0] = ri1[nt];
        mk[base + 1] = rv2[nt]; mi[base + 1] = ri2[nt];
        mk[base + 2] = rv3[nt]; mi[base + 2] = ri3[nt];
    }
    __syncthreads();
    {
        unsigned b1 = 0u, b2 = 0u, b3 = 0u;
        int i1 = 0x7FFFFFFF, i2 = 0x7FFFFFFF, i3 = 0x7FFFFFFF;
        #pragma unroll
        for (int j = 0; j < 6; ++j) {
            unsigned k = mk[t * 6 + j]; int i = mi[t * 6 + j];
            if (k > b1 || (k == b1 && i < i1)) {
                b3 = b2; i3 = i2; b2 = b1; i2 = i1; b1 = k; i1 = i;
            } else if (k > b2 || (k == b2 && i < i2)) {
                b3 = b2; i3 = i2; b2 = k; i2 = i;
            } else if (k > b3 || (k == b3 && i < i3)) {
                b3 = k; i3 = i;
            }
        }
        size_t base = ((size_t)part * N_TOK + tokBase + t) * 3;
        cand[base + 0] = {b1, (unsigned)i1};
        cand[base + 1] = {b2, (unsigned)i2};
        cand[base + 2] = {b3, (unsigned)i3};
    }
}

// ---------------------------------------------------------------------------
// Kernel 3 (R6-fused structure, 24 candidates): margin-gated rescore +
// gather. Block per (b,h) = 32 tokens. Merge 24 (key,idx) pairs (8
// partitions x 3); if key1-key2 > 2048 ULP the scan decided -> done. Else
// rescore ONLY candidates with key >= best-8192 ULP (superset of possible
// winners) in exact fp32, jnp.argmin tie semantics. Then gather +
// transpose-write.
// ---------------------------------------------------------------------------
__global__ __launch_bounds__(256) void rescore_gather(
        const float* __restrict__ ztn, const float* __restrict__ e_n,
        const float* __restrict__ s2, const uint2* __restrict__ cand,
        float* __restrict__ out, float* __restrict__ idxf) {
    __shared__ __align__(16) char sm[32 * 257 * 4];
    __shared__ uint2 cd[32][24];
    __shared__ int idxs[32];
    __shared__ int slowlist[32];
    __shared__ unsigned bkey[32];
    __shared__ int nslow;
    float* tile = (float*)sm;        // [32][257] (phase C)
    int t = threadIdx.x;
    int bid = blockIdx.x;            // b*32 + h
    int b = bid >> 5, h = bid & 31;
    int n_base = bid * 32;
    int wv = t >> 6, l = t & 63;

    if (t == 0) nslow = 0;
    {
        int tok = t >> 3, p = t & 7;
        int n = n_base + tok;
        #pragma unroll
        for (int slot = 0; slot < 3; ++slot) {
            cd[tok][p * 3 + slot] = cand[((size_t)p * N_TOK + n) * 3 + slot];
        }
    }
    __syncthreads();

    if (t < 32) {
        unsigned b1k = 0u, b2k = 0u; int b1i = 0x7FFFFFFF, b2i = 0x7FFFFFFF;
        #pragma unroll
        for (int p = 0; p < 24; ++p) {
            uint2 c2 = cd[t][p];
            unsigned k = c2.x; int i = (int)c2.y;
            if (k > b1k || (k == b1k && i < b1i)) { b2k = b1k; b2i = b1i; b1k = k; b1i = i; }
            else if (k > b2k || (k == b2k && i < b2i)) { b2k = k; b2i = i; }
        }
        bkey[t] = b1k;
        if (b1k - b2k > 2048u) {        // scan-decided
            idxs[t] = b1i;
            idxf[n_base + t] = (float)b1i;
        } else {
            int s = atomicAdd(&nslow, 1);
            slowlist[s] = t;
        }
    }
    __syncthreads();
    int ns = nslow;
    // slow path: one wave per token; only candidates within 8192 ULP of the
    // token's best key are rescored (superset of possible true winners)
    for (int j = wv; j < ns; j += 4) {
        int tok = slowlist[j];
        int n = n_base + tok;
        unsigned bk = bkey[tok];
        float bs = FLT_MAX; int bi = 0x7FFFFFFF;
        if (l < 24) {
            uint2 c2 = cd[tok][l];
            if (c2.x + 8192u >= bk) {
                int c = (int)c2.y;
                const float* er = e_n + (size_t)c * C_DIM;
                const float* zr = ztn + (size_t)n * C_DIM;
                float s = 0.f;
                #pragma unroll
                for (int jj = 0; jj < 64; ++jj) {
                    float4 e4 = *(const float4*)(er + jj * 4);
                    float4 z4 = *(const float4*)(zr + jj * 4);
                    s = fmaf(e4.x, z4.x, s); s = fmaf(e4.y, z4.y, s);
                    s = fmaf(e4.z, z4.z, s); s = fmaf(e4.w, z4.w, s);
                }
                bs = s2[c] - 2.f * s;
                bi = c;
            }
        }
        #pragma unroll
        for (int d = 1; d < 64; d <<= 1) {
            float os = __shfl_xor(bs, d);
            int   oi = __shfl_xor(bi, d);
            if (os < bs || (os == bs && oi < bi)) { bs = os; bi = oi; }
        }
        if (l == 0) { idxs[tok] = bi; idxf[n] = (float)bi; }
    }
    __syncthreads();

    // Phase C: gather winning rows, transpose-write
    for (int r = 0; r < 32; ++r) {
        int k = idxs[r];
        tile[r * 257 + t] = e_n[(size_t)k * C_DIM + t];
    }
    __syncthreads();
    int w = t & 31, c0 = t >> 5;
    float* ob = out + ((size_t)(b * C_DIM) * H_ + h) * W_;
    #pragma unroll
    for (int it = 0; it < 32; ++it) {
        int c = it * 8 + c0;
        ob[(size_t)c * HW + w] = tile[w * 257 + c];
    }
}

// ---------------------------------------------------------------------------
extern "C" void kernel_launch(void* const* d_in, const int* in_sizes, int n_in,
                              void* d_out, int out_size, void* d_ws, size_t ws_size,
                              hipStream_t stream) {
    const float* z   = (const float*)d_in[0];
    const float* emb = (const float*)d_in[1];
    float* out  = (float*)d_out;
    float* idxf = out + (size_t)B_ * C_DIM * H_ * W_;

    char* ws = (char*)d_ws;
    size_t o = 0;
    float*  e_n  = (float*)(ws + o);  o += (size_t)K_CODES * C_DIM * 4;   // 8 MB
    float*  s2   = (float*)(ws + o);  o += 32768;
    float*  ztn  = (float*)(ws + o);  o += (size_t)N_TOK * C_DIM * 4;     // 16 MB
    ushort* Chi  = (ushort*)(ws + o); o += (size_t)K_CODES * C_DIM * 2;   // 4 MB
    ushort* Thi  = (ushort*)(ws + o); o += (size_t)N_TOK * C_DIM * 2;     // 8 MB
    uint2*  cand = (uint2*)(ws + o);  o += (size_t)KSPLIT * N_TOK * 3 * 8; // 3 MB

    hipLaunchKernelGGL(norm_pack, dim3(256 + B_ * H_), dim3(256), 0, stream,
                       emb, z, e_n, s2, Chi, ztn, Thi);
    hipLaunchKernelGGL(score_topk, dim3(N_TOK / TOKS_PER_BLK, KSPLIT), dim3(256), 0, stream,
                       Chi, Thi, cand);
    hipLaunchKernelGGL(rescore_gather, dim3(B_ * H_), dim3(256), 0, stream,
                       ztn, e_n, s2, cand, out, idxf);
}